// Round 18
// baseline (120.463 us; speedup 1.0000x reference)
//
#include <hip/hip_runtime.h>
#include <stdint.h>

#define B_ 2
#define T_ 2048
#define C_ 1024
#define H_ 16
#define D_ 64
#define M_ (B_*T_)
#define BHTD_ (B_*H_*T_*D_)

#define AS1 __attribute__((address_space(1)))
#define AS3 __attribute__((address_space(3)))

typedef __bf16 bf16x8 __attribute__((ext_vector_type(8)));
typedef __bf16 bf16x4 __attribute__((ext_vector_type(4)));
typedef float f32x4 __attribute__((ext_vector_type(4)));

static __device__ __forceinline__ unsigned short f32_bf16(float f) {
    unsigned int u = __float_as_uint(f);
    u += 0x7FFFu + ((u >> 16) & 1u);   // round-to-nearest-even
    return (unsigned short)(u >> 16);
}

// ---------------- fused prep: cast x + transpose both W (one launch) ----------------
__global__ void prep_kernel(const float* __restrict__ x, unsigned short* __restrict__ xbf,
                            const float* __restrict__ Wqkv, unsigned short* __restrict__ wqkv_t,
                            const float* __restrict__ Wproj, unsigned short* __restrict__ wproj_t) {
    __shared__ float tile[32][33];
    const int id = blockIdx.x;
    const int tid = threadIdx.x;
    if (id < 4096) {
        int i = (id * 256 + tid) * 4;
        float4 f = *(const float4*)(x + i);
        ushort4 o;
        o.x = f32_bf16(f.x); o.y = f32_bf16(f.y); o.z = f32_bf16(f.z); o.w = f32_bf16(f.w);
        *(ushort4*)(xbf + i) = o;
        return;
    }
    const float* W; unsigned short* Wt; int K, N, bx, by;
    if (id < 7168) {
        int r = id - 4096; W = Wqkv; Wt = wqkv_t; K = 1024; N = 3072;
        bx = r % 96; by = r / 96;
    } else {
        int r = id - 7168; W = Wproj; Wt = wproj_t; K = 1024; N = 1024;
        bx = r & 31; by = r >> 5;
    }
    int n0 = bx * 32, k0 = by * 32;
    int tx = tid & 31, ty = tid >> 5;
    #pragma unroll
    for (int j = 0; j < 32; j += 8)
        tile[ty + j][tx] = W[(size_t)(k0 + ty + j) * N + n0 + tx];
    __syncthreads();
    #pragma unroll
    for (int j = 0; j < 32; j += 8)
        Wt[(size_t)(n0 + ty + j) * K + k0 + tx] = f32_bf16(tile[tx][ty + j]);
}

// ---------------- GEMM: 2-phase dbuf gll staging; tile 128 x BN (round-17 proven) ----------------
template<int EPI, int BN>
__global__ __launch_bounds__(256) void gemm_bt(
    const unsigned short* __restrict__ A,
    const unsigned short* __restrict__ Bt,
    const float* __restrict__ bias,
    unsigned short* __restrict__ out_bf16,
    float* __restrict__ out_f32,
    int M, int N, int K)
{
    constexpr int NI = (BN == 128) ? 4 : 2;
    constexpr int BSTR = BN * 32;
    __shared__ __align__(16) unsigned short smem[16640];
    unsigned short* AsU = smem;
    unsigned short* BsU = smem + 8192;
    int tid = threadIdx.x;
    int lane = tid & 63, wid = tid >> 6;
    int fr = lane & 15, fg = lane >> 4;
    int row0 = blockIdx.x * 128, col0 = blockIdx.y * BN;
    int wm = (wid >> 1) * 64, wn = (wid & 1) * (BN / 2);

    f32x4 acc[4][NI];
    #pragma unroll
    for (int i = 0; i < 4; ++i)
        #pragma unroll
        for (int j = 0; j < NI; ++j)
            acc[i][j] = (f32x4){0.f, 0.f, 0.f, 0.f};

    const int srw = lane >> 2;
    const int scl = (lane & 3) * 8;
    const int c0 = wid * 2, c1 = wid * 2 + 1;

    auto stage = [&](int buf, int k0) {
        __builtin_amdgcn_global_load_lds(
            (const AS1 void*)(A + (size_t)(row0 + c0 * 16 + srw) * K + k0 + scl),
            (AS3 void*)(AsU + buf * 4096 + c0 * 512), 16, 0, 0);
        __builtin_amdgcn_global_load_lds(
            (const AS1 void*)(A + (size_t)(row0 + c1 * 16 + srw) * K + k0 + scl),
            (AS3 void*)(AsU + buf * 4096 + c1 * 512), 16, 0, 0);
        if (BN == 128) {
            __builtin_amdgcn_global_load_lds(
                (const AS1 void*)(Bt + (size_t)(col0 + c0 * 16 + srw) * K + k0 + scl),
                (AS3 void*)(BsU + buf * BSTR + c0 * 512), 16, 0, 0);
            __builtin_amdgcn_global_load_lds(
                (const AS1 void*)(Bt + (size_t)(col0 + c1 * 16 + srw) * K + k0 + scl),
                (AS3 void*)(BsU + buf * BSTR + c1 * 512), 16, 0, 0);
        } else {
            __builtin_amdgcn_global_load_lds(
                (const AS1 void*)(Bt + (size_t)(col0 + wid * 16 + srw) * K + k0 + scl),
                (AS3 void*)(BsU + buf * BSTR + wid * 512), 16, 0, 0);
        }
    };

    stage(0, 0);
    __syncthreads();

    int cur = 0;
    for (int k0 = 0; k0 < K; k0 += 32) {
        if (k0 + 32 < K) stage(cur ^ 1, k0 + 32);

        bf16x8 af[4], bfr[NI];
        #pragma unroll
        for (int i = 0; i < 4; ++i)
            af[i] = *(const bf16x8*)(AsU + cur * 4096 + (wm + i * 16 + fr) * 32 + fg * 8);
        #pragma unroll
        for (int i = 0; i < NI; ++i)
            bfr[i] = *(const bf16x8*)(BsU + cur * BSTR + (wn + i * 16 + fr) * 32 + fg * 8);
        #pragma unroll
        for (int mi = 0; mi < 4; ++mi)
            #pragma unroll
            for (int ni = 0; ni < NI; ++ni)
                acc[mi][ni] = __builtin_amdgcn_mfma_f32_16x16x32_bf16(af[mi], bfr[ni], acc[mi][ni], 0, 0, 0);

        __syncthreads();
        cur ^= 1;
    }

    if (EPI == 0 && col0 >= 2048) {
        // ---- V blocks: transpose through LDS, coalesced [d][T] stores ----
        #pragma unroll
        for (int ni = 0; ni < NI; ++ni) {
            const int cl = wn + ni * 16 + fr;
            const float bv = bias[col0 + cl];
            #pragma unroll
            for (int mi = 0; mi < 4; ++mi) {
                const int rl = wm + mi * 16 + fg * 4;
                bf16x4 pk = {(__bf16)(acc[mi][ni][0] + bv), (__bf16)(acc[mi][ni][1] + bv),
                             (__bf16)(acc[mi][ni][2] + bv), (__bf16)(acc[mi][ni][3] + bv)};
                uint2 w = __builtin_bit_cast(uint2, pk);
                *(unsigned int*)(smem + cl * 130 + rl)     = w.x;
                *(unsigned int*)(smem + cl * 130 + rl + 2) = w.y;
            }
        }
        __syncthreads();
        constexpr int TPC = 256 / BN;
        constexpr int SEG = 128 / TPC;
        const int c = tid / TPC, seg = tid % TPC;
        const int col = col0 + c;
        const int d = col & 63, h2 = (col >> 6) & 15;
        const int bb = row0 >> 11;
        const int t0 = (row0 & 2047) + seg * SEG;
        unsigned short* dst = out_bf16 + (size_t)2 * BHTD_ +
                              ((size_t)(bb * H_ + h2) * D_ + d) * T_ + t0;
        const unsigned short* src = smem + c * 130 + seg * SEG;
        #pragma unroll
        for (int j = 0; j < SEG / 8; ++j) {
            uint4 v;
            v.x = *(const unsigned int*)(src + j * 8 + 0);
            v.y = *(const unsigned int*)(src + j * 8 + 2);
            v.z = *(const unsigned int*)(src + j * 8 + 4);
            v.w = *(const unsigned int*)(src + j * 8 + 6);
            *(uint4*)(dst + j * 8) = v;
        }
        return;
    }

    #pragma unroll
    for (int mi = 0; mi < 4; ++mi) {
        int rowb = row0 + wm + mi * 16 + fg * 4;
        #pragma unroll
        for (int ni = 0; ni < NI; ++ni) {
            int col = col0 + wn + ni * 16 + fr;
            float bv = bias[col];
            #pragma unroll
            for (int r = 0; r < 4; ++r) {
                float v = acc[mi][ni][r] + bv;
                int rr = rowb + r;
                if (EPI == 0) {
                    int part = col >> 10, c = col & 1023;
                    int h = c >> 6, d = c & 63;
                    int b = rr >> 11, t = rr & 2047;
                    if (part == 0) v *= 0.18033688011112042f;   // fold log2(e)/sqrt(D) into Q
                    size_t idx = (size_t)part * BHTD_ + ((size_t)(b * H_ + h) * T_ + t) * D_ + d;
                    out_bf16[idx] = f32_bf16(v);
                } else {
                    out_f32[(size_t)rr * N + col] = v;
                }
            }
        }
    }
}

// ---------------- causal flash attention v14: v13 math, half-row blocks ----------------
// 1024 blocks x 128 threads (2 waves). Sibling blocks split each 64-row
// chunk-pair: block handles 32 rows (sub*32) of hi chunk AND lo chunk, each
// wave 16 rows/stream (per-wave code IDENTICAL to v13). LDS 40KB ->
// EXACTLY 4 blocks/CU resident = 4 waves/SIMD (2x TLP vs v13).
// Cost: K/V staged twice per chunk-pair (L2-resident, absorbed).
__global__ __launch_bounds__(128) void attn_kernel(
    const unsigned short* __restrict__ qg,
    const unsigned short* __restrict__ kg,
    const unsigned short* __restrict__ vtg,  // [bh][D][T]
    unsigned short* __restrict__ y)
{
    const int id = blockIdx.x;
    const int xcd = id & 7, loc = id >> 3;      // loc in [0,128)
    const int bh = xcd * 4 + (loc & 3);         // 4 heads per XCD -> K/V L2-resident
    const int iq0 = (loc >> 2) & 15;            // [0,16)
    const int sub = loc >> 6;                   // row half of the chunk
    const int iq = (iq0 < 8) ? iq0 : 23 - iq0;
    const int chlo = iq, chhi = 31 - iq;
    const int b = bh >> 4, h = bh & 15;
    const int tid = threadIdx.x, wid = tid >> 6, lane = tid & 63;
    const int fr = lane & 15, fg = lane >> 4;

    const unsigned short* qp = qg + (size_t)bh * (T_ * D_);
    const char* kpB = (const char*)(kg + (size_t)bh * (T_ * D_));
    const char* vpB = (const char*)(vtg + (size_t)bh * (D_ * T_));

    __shared__ __align__(16) char Ks[2][8192];       // [kv][128B], XOR-swizzled
    __shared__ __align__(16) char Vs[2][8192];       // [d][128B], XOR-swizzled
    __shared__ __align__(16) char Ps[2][32 * 128];   // per-wave P: [stream*16+row][kv]
    char* Pw = Ps[wid];

    const int rhi = chhi * 64 + sub * 32 + wid * 16;
    const int rlo = chlo * 64 + sub * 32 + wid * 16;

    bf16x8 qhi[2], qlo[2];
    #pragma unroll
    for (int kd = 0; kd < 2; ++kd) {
        qhi[kd] = *(const bf16x8*)(qp + (size_t)(rhi + fr) * D_ + kd * 32 + fg * 8);
        qlo[kd] = *(const bf16x8*)(qp + (size_t)(rlo + fr) * D_ + kd * 32 + fg * 8);
    }

    f32x4 oHi[4], oLo[4];
    float lHi = 0.f, lLo = 0.f;
    #pragma unroll
    for (int n = 0; n < 4; ++n) {
        oHi[n] = (f32x4){0.f, 0.f, 0.f, 0.f};
        oLo[n] = (f32x4){0.f, 0.f, 0.f, 0.f};
    }

    const int ntk  = chhi + 1;
    const int ntlo = chlo + 1;

    // gll staging: per wave 4 K-chunks + 4 V-chunks of 8 rows (1KB each)
    const int srow8 = lane >> 3;
    const int scol  = (lane & 7) * 16;
    const int ssw   = srow8 << 4;

    auto stage = [&](int buf, int kv0) {
        #pragma unroll
        for (int bc = 0; bc < 4; ++bc) {
            const int rbase = wid * 32 + bc * 8;
            __builtin_amdgcn_global_load_lds(
                (const AS1 void*)(kpB + (size_t)(kv0 + rbase + srow8) * 128 + (scol ^ ssw)),
                (AS3 void*)(Ks[buf] + rbase * 128), 16, 0, 0);
            __builtin_amdgcn_global_load_lds(
                (const AS1 void*)(vpB + (size_t)(rbase + srow8) * 4096 + (size_t)kv0 * 2 + (scol ^ ssw)),
                (AS3 void*)(Vs[buf] + rbase * 128), 16, 0, 0);
        }
    };

    stage(0, 0);
    __syncthreads();

    const unsigned lsw = (unsigned)((fr & 7) << 4);
    int cur = 0;
    for (int t = 0; t < ntk; ++t) {
        const int kv0 = t * 64;
        if (t + 1 < ntk) stage(cur ^ 1, kv0 + 64);

        const char* Kb = Ks[cur];
        const char* Vb = Vs[cur];
        const bool lo_act = (t < ntlo);

        f32x4 sh[4], sl[4];
        #pragma unroll
        for (int n = 0; n < 4; ++n) {
            sh[n] = (f32x4){0.f, 0.f, 0.f, 0.f};
            sl[n] = (f32x4){0.f, 0.f, 0.f, 0.f};
        }
        __builtin_amdgcn_s_setprio(1);
        #pragma unroll
        for (int kd = 0; kd < 2; ++kd)
            #pragma unroll
            for (int n = 0; n < 4; ++n) {
                bf16x8 kf = *(const bf16x8*)(Kb + (n * 16 + fr) * 128 +
                                             (((unsigned)(kd * 64 + fg * 16)) ^ lsw));
                sh[n] = __builtin_amdgcn_mfma_f32_16x16x32_bf16(kf, qhi[kd], sh[n], 0, 0, 0);
                if (lo_act)
                    sl[n] = __builtin_amdgcn_mfma_f32_16x16x32_bf16(kf, qlo[kd], sl[n], 0, 0, 0);
            }
        __builtin_amdgcn_s_setprio(0);

        bf16x8 vf[4][2];
        #pragma unroll
        for (int nd = 0; nd < 4; ++nd)
            #pragma unroll
            for (int kk = 0; kk < 2; ++kk)
                vf[nd][kk] = *(const bf16x8*)(Vb + (nd * 16 + fr) * 128 +
                                              (((unsigned)(kk * 64 + fg * 16)) ^ lsw));

        {
            const bool masked = (t == chhi);
            const int qrow = rhi + fr;
            const unsigned prow = (unsigned)fr * 128;
            #pragma unroll
            for (int n = 0; n < 4; ++n) {
                float x0 = sh[n][0], x1 = sh[n][1], x2 = sh[n][2], x3 = sh[n][3];
                if (masked) {
                    const int kvb = kv0 + n * 16 + fg * 4;
                    if (kvb     > qrow) x0 = -1e30f;
                    if (kvb + 1 > qrow) x1 = -1e30f;
                    if (kvb + 2 > qrow) x2 = -1e30f;
                    if (kvb + 3 > qrow) x3 = -1e30f;
                }
                const float p0 = __builtin_amdgcn_exp2f(x0);
                const float p1 = __builtin_amdgcn_exp2f(x1);
                const float p2 = __builtin_amdgcn_exp2f(x2);
                const float p3 = __builtin_amdgcn_exp2f(x3);
                lHi += (p0 + p1) + (p2 + p3);
                bf16x4 pk4 = {(__bf16)p0, (__bf16)p1, (__bf16)p2, (__bf16)p3};
                *(uint2*)(Pw + ((prow + (unsigned)(n * 32 + fg * 8)) ^ lsw)) =
                    __builtin_bit_cast(uint2, pk4);
            }
        }
        {
            const unsigned prow = (unsigned)fr * 128;
            __builtin_amdgcn_s_setprio(1);
            #pragma unroll
            for (int kk = 0; kk < 2; ++kk) {
                bf16x8 pb = *(const bf16x8*)(Pw + ((prow + (unsigned)(kk * 64 + fg * 16)) ^ lsw));
                #pragma unroll
                for (int nd = 0; nd < 4; ++nd)
                    oHi[nd] = __builtin_amdgcn_mfma_f32_16x16x32_bf16(vf[nd][kk], pb, oHi[nd], 0, 0, 0);
            }
            __builtin_amdgcn_s_setprio(0);
        }
        if (lo_act) {
            const bool masked = (t == chlo);
            const int qrow = rlo + fr;
            const unsigned prow = (unsigned)(16 + fr) * 128;
            #pragma unroll
            for (int n = 0; n < 4; ++n) {
                float x0 = sl[n][0], x1 = sl[n][1], x2 = sl[n][2], x3 = sl[n][3];
                if (masked) {
                    const int kvb = kv0 + n * 16 + fg * 4;
                    if (kvb     > qrow) x0 = -1e30f;
                    if (kvb + 1 > qrow) x1 = -1e30f;
                    if (kvb + 2 > qrow) x2 = -1e30f;
                    if (kvb + 3 > qrow) x3 = -1e30f;
                }
                const float p0 = __builtin_amdgcn_exp2f(x0);
                const float p1 = __builtin_amdgcn_exp2f(x1);
                const float p2 = __builtin_amdgcn_exp2f(x2);
                const float p3 = __builtin_amdgcn_exp2f(x3);
                lLo += (p0 + p1) + (p2 + p3);
                bf16x4 pk4 = {(__bf16)p0, (__bf16)p1, (__bf16)p2, (__bf16)p3};
                *(uint2*)(Pw + ((prow + (unsigned)(n * 32 + fg * 8)) ^ lsw)) =
                    __builtin_bit_cast(uint2, pk4);
            }
            __builtin_amdgcn_s_setprio(1);
            #pragma unroll
            for (int kk = 0; kk < 2; ++kk) {
                bf16x8 pb = *(const bf16x8*)(Pw + ((prow + (unsigned)(kk * 64 + fg * 16)) ^ lsw));
                #pragma unroll
                for (int nd = 0; nd < 4; ++nd)
                    oLo[nd] = __builtin_amdgcn_mfma_f32_16x16x32_bf16(vf[nd][kk], pb, oLo[nd], 0, 0, 0);
            }
            __builtin_amdgcn_s_setprio(0);
        }

        __syncthreads();
        cur ^= 1;
    }

    #pragma unroll
    for (int s = 0; s < 2; ++s) {
        float rs = s ? lLo : lHi;
        rs += __shfl_xor(rs, 16);
        rs += __shfl_xor(rs, 32);
        const float inv = 1.f / rs;
        const int trow = (s ? rlo : rhi) + fr;
        f32x4* oT = s ? oLo : oHi;
        #pragma unroll
        for (int nd = 0; nd < 4; ++nd) {
            bf16x4 ov = {(__bf16)(oT[nd][0] * inv), (__bf16)(oT[nd][1] * inv),
                         (__bf16)(oT[nd][2] * inv), (__bf16)(oT[nd][3] * inv)};
            *(uint2*)(y + ((size_t)b * T_ + trow) * C_ + h * 64 + nd * 16 + fg * 4) =
                __builtin_bit_cast(uint2, ov);
        }
    }
}

// ---------------- launch ----------------
extern "C" void kernel_launch(void* const* d_in, const int* in_sizes, int n_in,
                              void* d_out, int out_size, void* d_ws, size_t ws_size,
                              hipStream_t stream) {
    const float* x     = (const float*)d_in[0];
    const float* Wqkv  = (const float*)d_in[1];
    const float* bqkv  = (const float*)d_in[2];
    const float* Wproj = (const float*)d_in[3];
    const float* bproj = (const float*)d_in[4];
    float* out = (float*)d_out;

    char* ws = (char*)d_ws;
    unsigned short* x_bf    = (unsigned short*)(ws);                 //  8 MB
    unsigned short* wqkv_t  = (unsigned short*)(ws + 8388608);       //  6 MB
    unsigned short* wproj_t = (unsigned short*)(ws + 14680064);      //  2 MB
    unsigned short* qkv     = (unsigned short*)(ws + 16777216);      // 24 MB
    unsigned short* ybuf    = (unsigned short*)(ws + 41943040);      //  8 MB

    prep_kernel<<<dim3(8192), 256, 0, stream>>>(x, x_bf, Wqkv, wqkv_t, Wproj, wproj_t);

    gemm_bt<0, 64><<<dim3(M_ / 128, 3072 / 64), 256, 0, stream>>>(
        x_bf, wqkv_t, bqkv, qkv, nullptr, M_, 3072, 1024);

    attn_kernel<<<dim3(1024), 128, 0, stream>>>(
        qkv, qkv + (size_t)BHTD_, qkv + 2 * (size_t)BHTD_, ybuf);

    gemm_bt<1, 64><<<dim3(M_ / 128, 1024 / 64), 256, 0, stream>>>(
        ybuf, wproj_t, bproj, nullptr, out, M_, 1024, 1024);
}

// Round 19
// 116.150 us; speedup vs baseline: 1.0371x; 1.0371x over previous
//
#include <hip/hip_runtime.h>
#include <stdint.h>

#define B_ 2
#define T_ 2048
#define C_ 1024
#define H_ 16
#define D_ 64
#define M_ (B_*T_)
#define BHTD_ (B_*H_*T_*D_)

#define AS1 __attribute__((address_space(1)))
#define AS3 __attribute__((address_space(3)))

typedef __bf16 bf16x8 __attribute__((ext_vector_type(8)));
typedef __bf16 bf16x4 __attribute__((ext_vector_type(4)));
typedef float f32x4 __attribute__((ext_vector_type(4)));

static __device__ __forceinline__ unsigned short f32_bf16(float f) {
    unsigned int u = __float_as_uint(f);
    u += 0x7FFFu + ((u >> 16) & 1u);   // round-to-nearest-even
    return (unsigned short)(u >> 16);
}

// ---------------- fused prep: cast x (32B/thread) + transpose both W ----------------
// blocks [0,2048): cast x f32->bf16 (8 elems/thread);
// [2048,5120): Wqkv transpose; [5120,6144): Wproj transpose.
__global__ void prep_kernel(const float* __restrict__ x, unsigned short* __restrict__ xbf,
                            const float* __restrict__ Wqkv, unsigned short* __restrict__ wqkv_t,
                            const float* __restrict__ Wproj, unsigned short* __restrict__ wproj_t) {
    __shared__ float tile[32][33];
    const int id = blockIdx.x;
    const int tid = threadIdx.x;
    if (id < 2048) {
        int i = (id * 256 + tid) * 8;
        float4 f0 = *(const float4*)(x + i);
        float4 f1 = *(const float4*)(x + i + 4);
        ushort4 o0, o1;
        o0.x = f32_bf16(f0.x); o0.y = f32_bf16(f0.y); o0.z = f32_bf16(f0.z); o0.w = f32_bf16(f0.w);
        o1.x = f32_bf16(f1.x); o1.y = f32_bf16(f1.y); o1.z = f32_bf16(f1.z); o1.w = f32_bf16(f1.w);
        uint4 w;
        w.x = __builtin_bit_cast(unsigned int, *(ushort2*)&o0.x);
        w.y = __builtin_bit_cast(unsigned int, *(ushort2*)&o0.z);
        w.z = __builtin_bit_cast(unsigned int, *(ushort2*)&o1.x);
        w.w = __builtin_bit_cast(unsigned int, *(ushort2*)&o1.z);
        *(uint4*)(xbf + i) = w;
        return;
    }
    const float* W; unsigned short* Wt; int K, N, bx, by;
    if (id < 5120) {
        int r = id - 2048; W = Wqkv; Wt = wqkv_t; K = 1024; N = 3072;
        bx = r % 96; by = r / 96;
    } else {
        int r = id - 5120; W = Wproj; Wt = wproj_t; K = 1024; N = 1024;
        bx = r & 31; by = r >> 5;
    }
    int n0 = bx * 32, k0 = by * 32;
    int tx = tid & 31, ty = tid >> 5;
    #pragma unroll
    for (int j = 0; j < 32; j += 8)
        tile[ty + j][tx] = W[(size_t)(k0 + ty + j) * N + n0 + tx];
    __syncthreads();
    #pragma unroll
    for (int j = 0; j < 32; j += 8)
        Wt[(size_t)(n0 + ty + j) * K + k0 + tx] = f32_bf16(tile[tx][ty + j]);
}

// ---------------- GEMM: 2-phase dbuf gll staging; tile 128 x BN (round-17 proven) ----------------
template<int EPI, int BN>
__global__ __launch_bounds__(256) void gemm_bt(
    const unsigned short* __restrict__ A,
    const unsigned short* __restrict__ Bt,
    const float* __restrict__ bias,
    unsigned short* __restrict__ out_bf16,
    float* __restrict__ out_f32,
    int M, int N, int K)
{
    constexpr int NI = (BN == 128) ? 4 : 2;
    constexpr int BSTR = BN * 32;
    __shared__ __align__(16) unsigned short smem[16640];
    unsigned short* AsU = smem;
    unsigned short* BsU = smem + 8192;
    int tid = threadIdx.x;
    int lane = tid & 63, wid = tid >> 6;
    int fr = lane & 15, fg = lane >> 4;
    int row0 = blockIdx.x * 128, col0 = blockIdx.y * BN;
    int wm = (wid >> 1) * 64, wn = (wid & 1) * (BN / 2);

    f32x4 acc[4][NI];
    #pragma unroll
    for (int i = 0; i < 4; ++i)
        #pragma unroll
        for (int j = 0; j < NI; ++j)
            acc[i][j] = (f32x4){0.f, 0.f, 0.f, 0.f};

    const int srw = lane >> 2;
    const int scl = (lane & 3) * 8;
    const int c0 = wid * 2, c1 = wid * 2 + 1;

    auto stage = [&](int buf, int k0) {
        __builtin_amdgcn_global_load_lds(
            (const AS1 void*)(A + (size_t)(row0 + c0 * 16 + srw) * K + k0 + scl),
            (AS3 void*)(AsU + buf * 4096 + c0 * 512), 16, 0, 0);
        __builtin_amdgcn_global_load_lds(
            (const AS1 void*)(A + (size_t)(row0 + c1 * 16 + srw) * K + k0 + scl),
            (AS3 void*)(AsU + buf * 4096 + c1 * 512), 16, 0, 0);
        if (BN == 128) {
            __builtin_amdgcn_global_load_lds(
                (const AS1 void*)(Bt + (size_t)(col0 + c0 * 16 + srw) * K + k0 + scl),
                (AS3 void*)(BsU + buf * BSTR + c0 * 512), 16, 0, 0);
            __builtin_amdgcn_global_load_lds(
                (const AS1 void*)(Bt + (size_t)(col0 + c1 * 16 + srw) * K + k0 + scl),
                (AS3 void*)(BsU + buf * BSTR + c1 * 512), 16, 0, 0);
        } else {
            __builtin_amdgcn_global_load_lds(
                (const AS1 void*)(Bt + (size_t)(col0 + wid * 16 + srw) * K + k0 + scl),
                (AS3 void*)(BsU + buf * BSTR + wid * 512), 16, 0, 0);
        }
    };

    stage(0, 0);
    __syncthreads();

    int cur = 0;
    for (int k0 = 0; k0 < K; k0 += 32) {
        if (k0 + 32 < K) stage(cur ^ 1, k0 + 32);

        bf16x8 af[4], bfr[NI];
        #pragma unroll
        for (int i = 0; i < 4; ++i)
            af[i] = *(const bf16x8*)(AsU + cur * 4096 + (wm + i * 16 + fr) * 32 + fg * 8);
        #pragma unroll
        for (int i = 0; i < NI; ++i)
            bfr[i] = *(const bf16x8*)(BsU + cur * BSTR + (wn + i * 16 + fr) * 32 + fg * 8);
        #pragma unroll
        for (int mi = 0; mi < 4; ++mi)
            #pragma unroll
            for (int ni = 0; ni < NI; ++ni)
                acc[mi][ni] = __builtin_amdgcn_mfma_f32_16x16x32_bf16(af[mi], bfr[ni], acc[mi][ni], 0, 0, 0);

        __syncthreads();
        cur ^= 1;
    }

    if (EPI == 0 && col0 >= 2048) {
        // ---- V blocks: transpose through LDS, coalesced [d][T] stores ----
        #pragma unroll
        for (int ni = 0; ni < NI; ++ni) {
            const int cl = wn + ni * 16 + fr;
            const float bv = bias[col0 + cl];
            #pragma unroll
            for (int mi = 0; mi < 4; ++mi) {
                const int rl = wm + mi * 16 + fg * 4;
                bf16x4 pk = {(__bf16)(acc[mi][ni][0] + bv), (__bf16)(acc[mi][ni][1] + bv),
                             (__bf16)(acc[mi][ni][2] + bv), (__bf16)(acc[mi][ni][3] + bv)};
                uint2 w = __builtin_bit_cast(uint2, pk);
                *(unsigned int*)(smem + cl * 130 + rl)     = w.x;
                *(unsigned int*)(smem + cl * 130 + rl + 2) = w.y;
            }
        }
        __syncthreads();
        constexpr int TPC = 256 / BN;
        constexpr int SEG = 128 / TPC;
        const int c = tid / TPC, seg = tid % TPC;
        const int col = col0 + c;
        const int d = col & 63, h2 = (col >> 6) & 15;
        const int bb = row0 >> 11;
        const int t0 = (row0 & 2047) + seg * SEG;
        unsigned short* dst = out_bf16 + (size_t)2 * BHTD_ +
                              ((size_t)(bb * H_ + h2) * D_ + d) * T_ + t0;
        const unsigned short* src = smem + c * 130 + seg * SEG;
        #pragma unroll
        for (int j = 0; j < SEG / 8; ++j) {
            uint4 v;
            v.x = *(const unsigned int*)(src + j * 8 + 0);
            v.y = *(const unsigned int*)(src + j * 8 + 2);
            v.z = *(const unsigned int*)(src + j * 8 + 4);
            v.w = *(const unsigned int*)(src + j * 8 + 6);
            *(uint4*)(dst + j * 8) = v;
        }
        return;
    }

    #pragma unroll
    for (int mi = 0; mi < 4; ++mi) {
        int rowb = row0 + wm + mi * 16 + fg * 4;
        #pragma unroll
        for (int ni = 0; ni < NI; ++ni) {
            int col = col0 + wn + ni * 16 + fr;
            float bv = bias[col];
            #pragma unroll
            for (int r = 0; r < 4; ++r) {
                float v = acc[mi][ni][r] + bv;
                int rr = rowb + r;
                if (EPI == 0) {
                    int part = col >> 10, c = col & 1023;
                    int h = c >> 6, d = c & 63;
                    int b = rr >> 11, t = rr & 2047;
                    if (part == 0) v *= 0.18033688011112042f;   // fold log2(e)/sqrt(D) into Q
                    size_t idx = (size_t)part * BHTD_ + ((size_t)(b * H_ + h) * T_ + t) * D_ + d;
                    out_bf16[idx] = f32_bf16(v);
                } else {
                    out_f32[(size_t)rr * N + col] = v;
                }
            }
        }
    }
}

// ---------------- causal flash attention v13 (round-17 proven, unchanged) ----------------
__global__ __launch_bounds__(256) void attn_kernel(
    const unsigned short* __restrict__ qg,
    const unsigned short* __restrict__ kg,
    const unsigned short* __restrict__ vtg,  // [bh][D][T]
    unsigned short* __restrict__ y)
{
    const int id = blockIdx.x;
    const int xcd = id & 7, loc = id >> 3;
    const int bh = xcd * 4 + (loc & 3);      // 4 heads per XCD -> K/V L2-resident
    const int iq0 = loc >> 2;                // [0,16)
    const int iq = (iq0 < 8) ? iq0 : 23 - iq0;
    const int chlo = iq, chhi = 31 - iq;     // 64-row q chunks
    const int b = bh >> 4, h = bh & 15;
    const int tid = threadIdx.x, wid = tid >> 6, lane = tid & 63;
    const int fr = lane & 15, fg = lane >> 4;

    const unsigned short* qp = qg + (size_t)bh * (T_ * D_);
    const char* kpB = (const char*)(kg + (size_t)bh * (T_ * D_));
    const char* vpB = (const char*)(vtg + (size_t)bh * (D_ * T_));

    __shared__ __align__(16) char Ks[2][8192];       // [kv][128B], XOR-swizzled
    __shared__ __align__(16) char Vs[2][8192];       // [d][128B], XOR-swizzled
    __shared__ __align__(16) char Ps[4][32 * 128];   // per-wave P: [stream*16+row][kv]
    char* Pw = Ps[wid];

    const int rhi = chhi * 64 + wid * 16;
    const int rlo = chlo * 64 + wid * 16;

    bf16x8 qhi[2], qlo[2];
    #pragma unroll
    for (int kd = 0; kd < 2; ++kd) {
        qhi[kd] = *(const bf16x8*)(qp + (size_t)(rhi + fr) * D_ + kd * 32 + fg * 8);
        qlo[kd] = *(const bf16x8*)(qp + (size_t)(rlo + fr) * D_ + kd * 32 + fg * 8);
    }

    f32x4 oHi[4], oLo[4];
    float lHi = 0.f, lLo = 0.f;
    #pragma unroll
    for (int n = 0; n < 4; ++n) {
        oHi[n] = (f32x4){0.f, 0.f, 0.f, 0.f};
        oLo[n] = (f32x4){0.f, 0.f, 0.f, 0.f};
    }

    const int ntk  = chhi + 1;
    const int ntlo = chlo + 1;

    const int srow8 = lane >> 3;
    const int scol  = (lane & 7) * 16;
    const int ssw   = srow8 << 4;

    auto stage = [&](int buf, int kv0) {
        #pragma unroll
        for (int bc = 0; bc < 2; ++bc) {
            const int rbase = wid * 16 + bc * 8;
            __builtin_amdgcn_global_load_lds(
                (const AS1 void*)(kpB + (size_t)(kv0 + rbase + srow8) * 128 + (scol ^ ssw)),
                (AS3 void*)(Ks[buf] + rbase * 128), 16, 0, 0);
            __builtin_amdgcn_global_load_lds(
                (const AS1 void*)(vpB + (size_t)(rbase + srow8) * 4096 + (size_t)kv0 * 2 + (scol ^ ssw)),
                (AS3 void*)(Vs[buf] + rbase * 128), 16, 0, 0);
        }
    };

    stage(0, 0);
    __syncthreads();

    const unsigned lsw = (unsigned)((fr & 7) << 4);
    int cur = 0;
    for (int t = 0; t < ntk; ++t) {
        const int kv0 = t * 64;
        if (t + 1 < ntk) stage(cur ^ 1, kv0 + 64);

        const char* Kb = Ks[cur];
        const char* Vb = Vs[cur];
        const bool lo_act = (t < ntlo);

        f32x4 sh[4], sl[4];
        #pragma unroll
        for (int n = 0; n < 4; ++n) {
            sh[n] = (f32x4){0.f, 0.f, 0.f, 0.f};
            sl[n] = (f32x4){0.f, 0.f, 0.f, 0.f};
        }
        __builtin_amdgcn_s_setprio(1);
        #pragma unroll
        for (int kd = 0; kd < 2; ++kd)
            #pragma unroll
            for (int n = 0; n < 4; ++n) {
                bf16x8 kf = *(const bf16x8*)(Kb + (n * 16 + fr) * 128 +
                                             (((unsigned)(kd * 64 + fg * 16)) ^ lsw));
                sh[n] = __builtin_amdgcn_mfma_f32_16x16x32_bf16(kf, qhi[kd], sh[n], 0, 0, 0);
                if (lo_act)
                    sl[n] = __builtin_amdgcn_mfma_f32_16x16x32_bf16(kf, qlo[kd], sl[n], 0, 0, 0);
            }
        __builtin_amdgcn_s_setprio(0);

        bf16x8 vf[4][2];
        #pragma unroll
        for (int nd = 0; nd < 4; ++nd)
            #pragma unroll
            for (int kk = 0; kk < 2; ++kk)
                vf[nd][kk] = *(const bf16x8*)(Vb + (nd * 16 + fr) * 128 +
                                              (((unsigned)(kk * 64 + fg * 16)) ^ lsw));

        {
            const bool masked = (t == chhi);
            const int qrow = rhi + fr;
            const unsigned prow = (unsigned)fr * 128;
            #pragma unroll
            for (int n = 0; n < 4; ++n) {
                float x0 = sh[n][0], x1 = sh[n][1], x2 = sh[n][2], x3 = sh[n][3];
                if (masked) {
                    const int kvb = kv0 + n * 16 + fg * 4;
                    if (kvb     > qrow) x0 = -1e30f;
                    if (kvb + 1 > qrow) x1 = -1e30f;
                    if (kvb + 2 > qrow) x2 = -1e30f;
                    if (kvb + 3 > qrow) x3 = -1e30f;
                }
                const float p0 = __builtin_amdgcn_exp2f(x0);
                const float p1 = __builtin_amdgcn_exp2f(x1);
                const float p2 = __builtin_amdgcn_exp2f(x2);
                const float p3 = __builtin_amdgcn_exp2f(x3);
                lHi += (p0 + p1) + (p2 + p3);
                bf16x4 pk4 = {(__bf16)p0, (__bf16)p1, (__bf16)p2, (__bf16)p3};
                *(uint2*)(Pw + ((prow + (unsigned)(n * 32 + fg * 8)) ^ lsw)) =
                    __builtin_bit_cast(uint2, pk4);
            }
        }
        {
            const unsigned prow = (unsigned)fr * 128;
            __builtin_amdgcn_s_setprio(1);
            #pragma unroll
            for (int kk = 0; kk < 2; ++kk) {
                bf16x8 pb = *(const bf16x8*)(Pw + ((prow + (unsigned)(kk * 64 + fg * 16)) ^ lsw));
                #pragma unroll
                for (int nd = 0; nd < 4; ++nd)
                    oHi[nd] = __builtin_amdgcn_mfma_f32_16x16x32_bf16(vf[nd][kk], pb, oHi[nd], 0, 0, 0);
            }
            __builtin_amdgcn_s_setprio(0);
        }
        if (lo_act) {
            const bool masked = (t == chlo);
            const int qrow = rlo + fr;
            const unsigned prow = (unsigned)(16 + fr) * 128;
            #pragma unroll
            for (int n = 0; n < 4; ++n) {
                float x0 = sl[n][0], x1 = sl[n][1], x2 = sl[n][2], x3 = sl[n][3];
                if (masked) {
                    const int kvb = kv0 + n * 16 + fg * 4;
                    if (kvb     > qrow) x0 = -1e30f;
                    if (kvb + 1 > qrow) x1 = -1e30f;
                    if (kvb + 2 > qrow) x2 = -1e30f;
                    if (kvb + 3 > qrow) x3 = -1e30f;
                }
                const float p0 = __builtin_amdgcn_exp2f(x0);
                const float p1 = __builtin_amdgcn_exp2f(x1);
                const float p2 = __builtin_amdgcn_exp2f(x2);
                const float p3 = __builtin_amdgcn_exp2f(x3);
                lLo += (p0 + p1) + (p2 + p3);
                bf16x4 pk4 = {(__bf16)p0, (__bf16)p1, (__bf16)p2, (__bf16)p3};
                *(uint2*)(Pw + ((prow + (unsigned)(n * 32 + fg * 8)) ^ lsw)) =
                    __builtin_bit_cast(uint2, pk4);
            }
            __builtin_amdgcn_s_setprio(1);
            #pragma unroll
            for (int kk = 0; kk < 2; ++kk) {
                bf16x8 pb = *(const bf16x8*)(Pw + ((prow + (unsigned)(kk * 64 + fg * 16)) ^ lsw));
                #pragma unroll
                for (int nd = 0; nd < 4; ++nd)
                    oLo[nd] = __builtin_amdgcn_mfma_f32_16x16x32_bf16(vf[nd][kk], pb, oLo[nd], 0, 0, 0);
            }
            __builtin_amdgcn_s_setprio(0);
        }

        __syncthreads();
        cur ^= 1;
    }

    #pragma unroll
    for (int s = 0; s < 2; ++s) {
        float rs = s ? lLo : lHi;
        rs += __shfl_xor(rs, 16);
        rs += __shfl_xor(rs, 32);
        const float inv = 1.f / rs;
        const int trow = (s ? rlo : rhi) + fr;
        f32x4* oT = s ? oLo : oHi;
        #pragma unroll
        for (int nd = 0; nd < 4; ++nd) {
            bf16x4 ov = {(__bf16)(oT[nd][0] * inv), (__bf16)(oT[nd][1] * inv),
                         (__bf16)(oT[nd][2] * inv), (__bf16)(oT[nd][3] * inv)};
            *(uint2*)(y + ((size_t)b * T_ + trow) * C_ + h * 64 + nd * 16 + fg * 4) =
                __builtin_bit_cast(uint2, ov);
        }
    }
}

// ---------------- launch ----------------
extern "C" void kernel_launch(void* const* d_in, const int* in_sizes, int n_in,
                              void* d_out, int out_size, void* d_ws, size_t ws_size,
                              hipStream_t stream) {
    const float* x     = (const float*)d_in[0];
    const float* Wqkv  = (const float*)d_in[1];
    const float* bqkv  = (const float*)d_in[2];
    const float* Wproj = (const float*)d_in[3];
    const float* bproj = (const float*)d_in[4];
    float* out = (float*)d_out;

    char* ws = (char*)d_ws;
    unsigned short* x_bf    = (unsigned short*)(ws);                 //  8 MB
    unsigned short* wqkv_t  = (unsigned short*)(ws + 8388608);       //  6 MB
    unsigned short* wproj_t = (unsigned short*)(ws + 14680064);      //  2 MB
    unsigned short* qkv     = (unsigned short*)(ws + 16777216);      // 24 MB
    unsigned short* ybuf    = (unsigned short*)(ws + 41943040);      //  8 MB

    prep_kernel<<<dim3(6144), 256, 0, stream>>>(x, x_bf, Wqkv, wqkv_t, Wproj, wproj_t);

    gemm_bt<0, 64><<<dim3(M_ / 128, 3072 / 64), 256, 0, stream>>>(
        x_bf, wqkv_t, bqkv, qkv, nullptr, M_, 3072, 1024);

    attn_kernel<<<dim3(512), 256, 0, stream>>>(
        qkv, qkv + (size_t)BHTD_, qkv + 2 * (size_t)BHTD_, ybuf);

    gemm_bt<1, 64><<<dim3(M_ / 128, 1024 / 64), 256, 0, stream>>>(
        ybuf, wproj_t, bproj, nullptr, out, M_, 1024, 1024);
}

// Round 20
// 113.224 us; speedup vs baseline: 1.0639x; 1.0258x over previous
//
#include <hip/hip_runtime.h>
#include <stdint.h>

#define B_ 2
#define T_ 2048
#define C_ 1024
#define H_ 16
#define D_ 64
#define M_ (B_*T_)
#define BHTD_ (B_*H_*T_*D_)

#define AS1 __attribute__((address_space(1)))
#define AS3 __attribute__((address_space(3)))

typedef __bf16 bf16x8 __attribute__((ext_vector_type(8)));
typedef __bf16 bf16x4 __attribute__((ext_vector_type(4)));
typedef float f32x4 __attribute__((ext_vector_type(4)));

static __device__ __forceinline__ unsigned short f32_bf16(float f) {
    unsigned int u = __float_as_uint(f);
    u += 0x7FFFu + ((u >> 16) & 1u);   // round-to-nearest-even
    return (unsigned short)(u >> 16);
}

// ---------------- fused prep: cast x (32B/thread) + transpose both W ----------------
__global__ void prep_kernel(const float* __restrict__ x, unsigned short* __restrict__ xbf,
                            const float* __restrict__ Wqkv, unsigned short* __restrict__ wqkv_t,
                            const float* __restrict__ Wproj, unsigned short* __restrict__ wproj_t) {
    __shared__ float tile[32][33];
    const int id = blockIdx.x;
    const int tid = threadIdx.x;
    if (id < 2048) {
        int i = (id * 256 + tid) * 8;
        float4 f0 = *(const float4*)(x + i);
        float4 f1 = *(const float4*)(x + i + 4);
        ushort4 o0, o1;
        o0.x = f32_bf16(f0.x); o0.y = f32_bf16(f0.y); o0.z = f32_bf16(f0.z); o0.w = f32_bf16(f0.w);
        o1.x = f32_bf16(f1.x); o1.y = f32_bf16(f1.y); o1.z = f32_bf16(f1.z); o1.w = f32_bf16(f1.w);
        uint4 w;
        w.x = __builtin_bit_cast(unsigned int, *(ushort2*)&o0.x);
        w.y = __builtin_bit_cast(unsigned int, *(ushort2*)&o0.z);
        w.z = __builtin_bit_cast(unsigned int, *(ushort2*)&o1.x);
        w.w = __builtin_bit_cast(unsigned int, *(ushort2*)&o1.z);
        *(uint4*)(xbf + i) = w;
        return;
    }
    const float* W; unsigned short* Wt; int K, N, bx, by;
    if (id < 5120) {
        int r = id - 2048; W = Wqkv; Wt = wqkv_t; K = 1024; N = 3072;
        bx = r % 96; by = r / 96;
    } else {
        int r = id - 5120; W = Wproj; Wt = wproj_t; K = 1024; N = 1024;
        bx = r & 31; by = r >> 5;
    }
    int n0 = bx * 32, k0 = by * 32;
    int tx = tid & 31, ty = tid >> 5;
    #pragma unroll
    for (int j = 0; j < 32; j += 8)
        tile[ty + j][tx] = W[(size_t)(k0 + ty + j) * N + n0 + tx];
    __syncthreads();
    #pragma unroll
    for (int j = 0; j < 32; j += 8)
        Wt[(size_t)(n0 + ty + j) * K + k0 + tx] = f32_bf16(tile[tx][ty + j]);
}

// ---------------- QKV GEMM: 256x256 tile, 8 waves, 4-slot counted-vmcnt pipeline ----------------
// A [4096][1024], Bt [3072][1024] bf16; C scattered into qkv with Q-scale and
// V-transpose epilogue. K-tile BK=32; slot k%4; stage tile t+2 while computing t;
// "s_waitcnt vmcnt(4); s_barrier" per iteration (never drains to 0 in steady state).
__global__ __launch_bounds__(512, 1) void gemm_qkv(
    const unsigned short* __restrict__ A,
    const unsigned short* __restrict__ Bt,
    const float* __restrict__ bias,
    unsigned short* __restrict__ out_bf16)
{
    __shared__ __align__(16) char LDS[131072];    // 4 slots x (A 16K + B 16K)
    const int tid = threadIdx.x;
    const int lane = tid & 63, wid = tid >> 6;
    const int fr = lane & 15, fg = lane >> 4;
    const int row0 = blockIdx.x * 256, col0 = blockIdx.y * 256;
    const int wm = (wid >> 2) * 128;              // 2 M-waves x 128 rows
    const int wn = (wid & 3) * 64;                // 4 N-waves x 64 cols

    const char* Ab = (const char*)A;
    const char* Bb = (const char*)Bt;

    f32x4 acc[8][4];
    #pragma unroll
    for (int i = 0; i < 8; ++i)
        #pragma unroll
        for (int j = 0; j < 4; ++j)
            acc[i][j] = (f32x4){0.f, 0.f, 0.f, 0.f};

    // staging: per K-tile, A = 2 gll (128 rows each), B = 2 gll. 4 gll/wave/tile.
    // LDS dest linear (wave base + lane*16); source pre-swizzled by ((row&3)<<4).
    const int sR0 = tid >> 2;                     // row within 128-row chunk
    const int sC0 = (tid & 3) * 16;               // byte col within 64B row
    auto stage = [&](int slot, int kt) {
        char* base = LDS + slot * 32768;
        const size_t koff = (size_t)kt * 64;
        #pragma unroll
        for (int j = 0; j < 2; ++j) {
            const int R = j * 128 + sR0;
            const int colb = sC0 ^ ((R & 3) << 4);
            __builtin_amdgcn_global_load_lds(
                (const AS1 void*)(Ab + (size_t)(row0 + R) * 2048 + koff + colb),
                (AS3 void*)(base + j * 8192 + wid * 1024), 16, 0, 0);
            __builtin_amdgcn_global_load_lds(
                (const AS1 void*)(Bb + (size_t)(col0 + R) * 2048 + koff + colb),
                (AS3 void*)(base + 16384 + j * 8192 + wid * 1024), 16, 0, 0);
        }
    };

    const int nt = 32;                            // K=1024 / 32
    stage(0, 0);
    stage(1, 1);
    asm volatile("s_waitcnt vmcnt(4)\n\ts_barrier" ::: "memory");   // tile 0 resident

    const int swz = (fr & 3) << 4;
    for (int kt = 0; kt < nt; ++kt) {
        const char* Ak = LDS + (kt & 3) * 32768;
        const char* Bk = Ak + 16384;
        if (kt + 2 < nt) stage((kt + 2) & 3, kt + 2);

        bf16x8 bfr[4];
        #pragma unroll
        for (int ni = 0; ni < 4; ++ni)
            bfr[ni] = *(const bf16x8*)(Bk + (wn + ni * 16 + fr) * 64 + ((fg * 16) ^ swz));

        #pragma unroll
        for (int q = 0; q < 4; ++q) {
            bf16x8 a0 = *(const bf16x8*)(Ak + (wm + (2 * q) * 16 + fr) * 64 + ((fg * 16) ^ swz));
            bf16x8 a1 = *(const bf16x8*)(Ak + (wm + (2 * q + 1) * 16 + fr) * 64 + ((fg * 16) ^ swz));
            __builtin_amdgcn_s_setprio(1);
            #pragma unroll
            for (int ni = 0; ni < 4; ++ni) {
                acc[2 * q][ni]     = __builtin_amdgcn_mfma_f32_16x16x32_bf16(a0, bfr[ni], acc[2 * q][ni], 0, 0, 0);
                acc[2 * q + 1][ni] = __builtin_amdgcn_mfma_f32_16x16x32_bf16(a1, bfr[ni], acc[2 * q + 1][ni], 0, 0, 0);
            }
            __builtin_amdgcn_s_setprio(0);
        }

        if (kt + 2 < nt)
            asm volatile("s_waitcnt vmcnt(4)\n\ts_barrier" ::: "memory");  // tile kt+1 landed
        else if (kt + 1 < nt)
            asm volatile("s_waitcnt vmcnt(0)\n\ts_barrier" ::: "memory");  // tail drain
    }

    const int part = col0 >> 10;                  // block-uniform (256 | 1024)
    const int bb = row0 >> 11;

    if (part < 2) {
        // Q/K parts: direct scatter [bh][T][D] (fr-consecutive d = coalesced runs)
        const float qscale = (part == 0) ? 0.18033688011112042f : 1.0f;
        #pragma unroll
        for (int mi = 0; mi < 8; ++mi) {
            const int rr = row0 + wm + mi * 16 + fg * 4;
            const int t = rr & 2047;
            #pragma unroll
            for (int ni = 0; ni < 4; ++ni) {
                const int col = col0 + wn + ni * 16 + fr;
                const float bv = bias[col];
                const int c = col & 1023, h = c >> 6, d = c & 63;
                unsigned short* dst = out_bf16 + (size_t)part * BHTD_ +
                                      ((size_t)(bb * H_ + h) * T_) * D_ + d;
                #pragma unroll
                for (int r = 0; r < 4; ++r)
                    dst[(size_t)(t + r) * D_] = f32_bf16((acc[mi][ni][r] + bv) * qscale);
            }
        }
        return;
    }

    // V part: transpose through LDS (two 128-col passes), coalesced [d][T] stores
    __syncthreads();
    unsigned short* tbuf = (unsigned short*)LDS;
    #pragma unroll
    for (int hc = 0; hc < 2; ++hc) {
        if (((wid & 3) >> 1) == hc) {
            #pragma unroll
            for (int ni = 0; ni < 4; ++ni) {
                const int cl = (wn - hc * 128) + ni * 16 + fr;     // [0,128)
                const float bv = bias[col0 + hc * 128 + cl];
                #pragma unroll
                for (int mi = 0; mi < 8; ++mi) {
                    const int rl = wm + mi * 16 + fg * 4;
                    bf16x4 pk = {(__bf16)(acc[mi][ni][0] + bv), (__bf16)(acc[mi][ni][1] + bv),
                                 (__bf16)(acc[mi][ni][2] + bv), (__bf16)(acc[mi][ni][3] + bv)};
                    uint2 w = __builtin_bit_cast(uint2, pk);
                    *(unsigned int*)(tbuf + cl * 258 + rl)     = w.x;
                    *(unsigned int*)(tbuf + cl * 258 + rl + 2) = w.y;
                }
            }
        }
        __syncthreads();
        const int c = tid >> 2, seg = tid & 3;                      // 128 cols x 4 segs
        const int col = col0 + hc * 128 + c;
        const int d = col & 63, h2 = (col >> 6) & 15;
        const int t0 = (row0 & 2047) + seg * 64;
        unsigned short* dst = out_bf16 + (size_t)2 * BHTD_ +
                              ((size_t)(bb * H_ + h2) * D_ + d) * T_ + t0;
        const unsigned short* src = tbuf + c * 258 + seg * 64;
        #pragma unroll
        for (int j = 0; j < 8; ++j) {
            uint4 v;
            v.x = *(const unsigned int*)(src + j * 8 + 0);
            v.y = *(const unsigned int*)(src + j * 8 + 2);
            v.z = *(const unsigned int*)(src + j * 8 + 4);
            v.w = *(const unsigned int*)(src + j * 8 + 6);
            *(uint4*)(dst + j * 8) = v;
        }
        __syncthreads();
    }
}

// ---------------- proj GEMM: 2-phase dbuf gll staging; tile 128x64 (round-17 proven) ----------------
__global__ __launch_bounds__(256) void gemm_proj(
    const unsigned short* __restrict__ A,
    const unsigned short* __restrict__ Bt,
    const float* __restrict__ bias,
    float* __restrict__ out_f32,
    int M, int N, int K)
{
    constexpr int BN = 64;
    constexpr int NI = 2;
    constexpr int BSTR = BN * 32;
    __shared__ __align__(16) unsigned short smem[16640];
    unsigned short* AsU = smem;
    unsigned short* BsU = smem + 8192;
    int tid = threadIdx.x;
    int lane = tid & 63, wid = tid >> 6;
    int fr = lane & 15, fg = lane >> 4;
    int row0 = blockIdx.x * 128, col0 = blockIdx.y * BN;
    int wm = (wid >> 1) * 64, wn = (wid & 1) * (BN / 2);

    f32x4 acc[4][NI];
    #pragma unroll
    for (int i = 0; i < 4; ++i)
        #pragma unroll
        for (int j = 0; j < NI; ++j)
            acc[i][j] = (f32x4){0.f, 0.f, 0.f, 0.f};

    const int srw = lane >> 2;
    const int scl = (lane & 3) * 8;
    const int c0 = wid * 2, c1 = wid * 2 + 1;

    auto stage = [&](int buf, int k0) {
        __builtin_amdgcn_global_load_lds(
            (const AS1 void*)(A + (size_t)(row0 + c0 * 16 + srw) * K + k0 + scl),
            (AS3 void*)(AsU + buf * 4096 + c0 * 512), 16, 0, 0);
        __builtin_amdgcn_global_load_lds(
            (const AS1 void*)(A + (size_t)(row0 + c1 * 16 + srw) * K + k0 + scl),
            (AS3 void*)(AsU + buf * 4096 + c1 * 512), 16, 0, 0);
        __builtin_amdgcn_global_load_lds(
            (const AS1 void*)(Bt + (size_t)(col0 + wid * 16 + srw) * K + k0 + scl),
            (AS3 void*)(BsU + buf * BSTR + wid * 512), 16, 0, 0);
    };

    stage(0, 0);
    __syncthreads();

    int cur = 0;
    for (int k0 = 0; k0 < K; k0 += 32) {
        if (k0 + 32 < K) stage(cur ^ 1, k0 + 32);

        bf16x8 af[4], bfr[NI];
        #pragma unroll
        for (int i = 0; i < 4; ++i)
            af[i] = *(const bf16x8*)(AsU + cur * 4096 + (wm + i * 16 + fr) * 32 + fg * 8);
        #pragma unroll
        for (int i = 0; i < NI; ++i)
            bfr[i] = *(const bf16x8*)(BsU + cur * BSTR + (wn + i * 16 + fr) * 32 + fg * 8);
        #pragma unroll
        for (int mi = 0; mi < 4; ++mi)
            #pragma unroll
            for (int ni = 0; ni < NI; ++ni)
                acc[mi][ni] = __builtin_amdgcn_mfma_f32_16x16x32_bf16(af[mi], bfr[ni], acc[mi][ni], 0, 0, 0);

        __syncthreads();
        cur ^= 1;
    }

    #pragma unroll
    for (int mi = 0; mi < 4; ++mi) {
        int rowb = row0 + wm + mi * 16 + fg * 4;
        #pragma unroll
        for (int ni = 0; ni < NI; ++ni) {
            int col = col0 + wn + ni * 16 + fr;
            float bv = bias[col];
            #pragma unroll
            for (int r = 0; r < 4; ++r)
                out_f32[(size_t)(rowb + r) * N + col] = acc[mi][ni][r] + bv;
        }
    }
}

// ---------------- causal flash attention v13 (round-17 proven, unchanged) ----------------
__global__ __launch_bounds__(256) void attn_kernel(
    const unsigned short* __restrict__ qg,
    const unsigned short* __restrict__ kg,
    const unsigned short* __restrict__ vtg,  // [bh][D][T]
    unsigned short* __restrict__ y)
{
    const int id = blockIdx.x;
    const int xcd = id & 7, loc = id >> 3;
    const int bh = xcd * 4 + (loc & 3);
    const int iq0 = loc >> 2;
    const int iq = (iq0 < 8) ? iq0 : 23 - iq0;
    const int chlo = iq, chhi = 31 - iq;
    const int b = bh >> 4, h = bh & 15;
    const int tid = threadIdx.x, wid = tid >> 6, lane = tid & 63;
    const int fr = lane & 15, fg = lane >> 4;

    const unsigned short* qp = qg + (size_t)bh * (T_ * D_);
    const char* kpB = (const char*)(kg + (size_t)bh * (T_ * D_));
    const char* vpB = (const char*)(vtg + (size_t)bh * (D_ * T_));

    __shared__ __align__(16) char Ks[2][8192];
    __shared__ __align__(16) char Vs[2][8192];
    __shared__ __align__(16) char Ps[4][32 * 128];
    char* Pw = Ps[wid];

    const int rhi = chhi * 64 + wid * 16;
    const int rlo = chlo * 64 + wid * 16;

    bf16x8 qhi[2], qlo[2];
    #pragma unroll
    for (int kd = 0; kd < 2; ++kd) {
        qhi[kd] = *(const bf16x8*)(qp + (size_t)(rhi + fr) * D_ + kd * 32 + fg * 8);
        qlo[kd] = *(const bf16x8*)(qp + (size_t)(rlo + fr) * D_ + kd * 32 + fg * 8);
    }

    f32x4 oHi[4], oLo[4];
    float lHi = 0.f, lLo = 0.f;
    #pragma unroll
    for (int n = 0; n < 4; ++n) {
        oHi[n] = (f32x4){0.f, 0.f, 0.f, 0.f};
        oLo[n] = (f32x4){0.f, 0.f, 0.f, 0.f};
    }

    const int ntk  = chhi + 1;
    const int ntlo = chlo + 1;

    const int srow8 = lane >> 3;
    const int scol  = (lane & 7) * 16;
    const int ssw   = srow8 << 4;

    auto stage = [&](int buf, int kv0) {
        #pragma unroll
        for (int bc = 0; bc < 2; ++bc) {
            const int rbase = wid * 16 + bc * 8;
            __builtin_amdgcn_global_load_lds(
                (const AS1 void*)(kpB + (size_t)(kv0 + rbase + srow8) * 128 + (scol ^ ssw)),
                (AS3 void*)(Ks[buf] + rbase * 128), 16, 0, 0);
            __builtin_amdgcn_global_load_lds(
                (const AS1 void*)(vpB + (size_t)(rbase + srow8) * 4096 + (size_t)kv0 * 2 + (scol ^ ssw)),
                (AS3 void*)(Vs[buf] + rbase * 128), 16, 0, 0);
        }
    };

    stage(0, 0);
    __syncthreads();

    const unsigned lsw = (unsigned)((fr & 7) << 4);
    int cur = 0;
    for (int t = 0; t < ntk; ++t) {
        const int kv0 = t * 64;
        if (t + 1 < ntk) stage(cur ^ 1, kv0 + 64);

        const char* Kb = Ks[cur];
        const char* Vb = Vs[cur];
        const bool lo_act = (t < ntlo);

        f32x4 sh[4], sl[4];
        #pragma unroll
        for (int n = 0; n < 4; ++n) {
            sh[n] = (f32x4){0.f, 0.f, 0.f, 0.f};
            sl[n] = (f32x4){0.f, 0.f, 0.f, 0.f};
        }
        __builtin_amdgcn_s_setprio(1);
        #pragma unroll
        for (int kd = 0; kd < 2; ++kd)
            #pragma unroll
            for (int n = 0; n < 4; ++n) {
                bf16x8 kf = *(const bf16x8*)(Kb + (n * 16 + fr) * 128 +
                                             (((unsigned)(kd * 64 + fg * 16)) ^ lsw));
                sh[n] = __builtin_amdgcn_mfma_f32_16x16x32_bf16(kf, qhi[kd], sh[n], 0, 0, 0);
                if (lo_act)
                    sl[n] = __builtin_amdgcn_mfma_f32_16x16x32_bf16(kf, qlo[kd], sl[n], 0, 0, 0);
            }
        __builtin_amdgcn_s_setprio(0);

        bf16x8 vf[4][2];
        #pragma unroll
        for (int nd = 0; nd < 4; ++nd)
            #pragma unroll
            for (int kk = 0; kk < 2; ++kk)
                vf[nd][kk] = *(const bf16x8*)(Vb + (nd * 16 + fr) * 128 +
                                              (((unsigned)(kk * 64 + fg * 16)) ^ lsw));

        {
            const bool masked = (t == chhi);
            const int qrow = rhi + fr;
            const unsigned prow = (unsigned)fr * 128;
            #pragma unroll
            for (int n = 0; n < 4; ++n) {
                float x0 = sh[n][0], x1 = sh[n][1], x2 = sh[n][2], x3 = sh[n][3];
                if (masked) {
                    const int kvb = kv0 + n * 16 + fg * 4;
                    if (kvb     > qrow) x0 = -1e30f;
                    if (kvb + 1 > qrow) x1 = -1e30f;
                    if (kvb + 2 > qrow) x2 = -1e30f;
                    if (kvb + 3 > qrow) x3 = -1e30f;
                }
                const float p0 = __builtin_amdgcn_exp2f(x0);
                const float p1 = __builtin_amdgcn_exp2f(x1);
                const float p2 = __builtin_amdgcn_exp2f(x2);
                const float p3 = __builtin_amdgcn_exp2f(x3);
                lHi += (p0 + p1) + (p2 + p3);
                bf16x4 pk4 = {(__bf16)p0, (__bf16)p1, (__bf16)p2, (__bf16)p3};
                *(uint2*)(Pw + ((prow + (unsigned)(n * 32 + fg * 8)) ^ lsw)) =
                    __builtin_bit_cast(uint2, pk4);
            }
        }
        {
            const unsigned prow = (unsigned)fr * 128;
            __builtin_amdgcn_s_setprio(1);
            #pragma unroll
            for (int kk = 0; kk < 2; ++kk) {
                bf16x8 pb = *(const bf16x8*)(Pw + ((prow + (unsigned)(kk * 64 + fg * 16)) ^ lsw));
                #pragma unroll
                for (int nd = 0; nd < 4; ++nd)
                    oHi[nd] = __builtin_amdgcn_mfma_f32_16x16x32_bf16(vf[nd][kk], pb, oHi[nd], 0, 0, 0);
            }
            __builtin_amdgcn_s_setprio(0);
        }
        if (lo_act) {
            const bool masked = (t == chlo);
            const int qrow = rlo + fr;
            const unsigned prow = (unsigned)(16 + fr) * 128;
            #pragma unroll
            for (int n = 0; n < 4; ++n) {
                float x0 = sl[n][0], x1 = sl[n][1], x2 = sl[n][2], x3 = sl[n][3];
                if (masked) {
                    const int kvb = kv0 + n * 16 + fg * 4;
                    if (kvb     > qrow) x0 = -1e30f;
                    if (kvb + 1 > qrow) x1 = -1e30f;
                    if (kvb + 2 > qrow) x2 = -1e30f;
                    if (kvb + 3 > qrow) x3 = -1e30f;
                }
                const float p0 = __builtin_amdgcn_exp2f(x0);
                const float p1 = __builtin_amdgcn_exp2f(x1);
                const float p2 = __builtin_amdgcn_exp2f(x2);
                const float p3 = __builtin_amdgcn_exp2f(x3);
                lLo += (p0 + p1) + (p2 + p3);
                bf16x4 pk4 = {(__bf16)p0, (__bf16)p1, (__bf16)p2, (__bf16)p3};
                *(uint2*)(Pw + ((prow + (unsigned)(n * 32 + fg * 8)) ^ lsw)) =
                    __builtin_bit_cast(uint2, pk4);
            }
            __builtin_amdgcn_s_setprio(1);
            #pragma unroll
            for (int kk = 0; kk < 2; ++kk) {
                bf16x8 pb = *(const bf16x8*)(Pw + ((prow + (unsigned)(kk * 64 + fg * 16)) ^ lsw));
                #pragma unroll
                for (int nd = 0; nd < 4; ++nd)
                    oLo[nd] = __builtin_amdgcn_mfma_f32_16x16x32_bf16(vf[nd][kk], pb, oLo[nd], 0, 0, 0);
            }
            __builtin_amdgcn_s_setprio(0);
        }

        __syncthreads();
        cur ^= 1;
    }

    #pragma unroll
    for (int s = 0; s < 2; ++s) {
        float rs = s ? lLo : lHi;
        rs += __shfl_xor(rs, 16);
        rs += __shfl_xor(rs, 32);
        const float inv = 1.f / rs;
        const int trow = (s ? rlo : rhi) + fr;
        f32x4* oT = s ? oLo : oHi;
        #pragma unroll
        for (int nd = 0; nd < 4; ++nd) {
            bf16x4 ov = {(__bf16)(oT[nd][0] * inv), (__bf16)(oT[nd][1] * inv),
                         (__bf16)(oT[nd][2] * inv), (__bf16)(oT[nd][3] * inv)};
            *(uint2*)(y + ((size_t)b * T_ + trow) * C_ + h * 64 + nd * 16 + fg * 4) =
                __builtin_bit_cast(uint2, ov);
        }
    }
}

// ---------------- launch ----------------
extern "C" void kernel_launch(void* const* d_in, const int* in_sizes, int n_in,
                              void* d_out, int out_size, void* d_ws, size_t ws_size,
                              hipStream_t stream) {
    const float* x     = (const float*)d_in[0];
    const float* Wqkv  = (const float*)d_in[1];
    const float* bqkv  = (const float*)d_in[2];
    const float* Wproj = (const float*)d_in[3];
    const float* bproj = (const float*)d_in[4];
    float* out = (float*)d_out;

    char* ws = (char*)d_ws;
    unsigned short* x_bf    = (unsigned short*)(ws);                 //  8 MB
    unsigned short* wqkv_t  = (unsigned short*)(ws + 8388608);       //  6 MB
    unsigned short* wproj_t = (unsigned short*)(ws + 14680064);      //  2 MB
    unsigned short* qkv     = (unsigned short*)(ws + 16777216);      // 24 MB
    unsigned short* ybuf    = (unsigned short*)(ws + 41943040);      //  8 MB

    prep_kernel<<<dim3(6144), 256, 0, stream>>>(x, x_bf, Wqkv, wqkv_t, Wproj, wproj_t);

    gemm_qkv<<<dim3(M_ / 256, 3072 / 256), 512, 0, stream>>>(
        x_bf, wqkv_t, bqkv, qkv);

    attn_kernel<<<dim3(512), 256, 0, stream>>>(
        qkv, qkv + (size_t)BHTD_, qkv + 2 * (size_t)BHTD_, ybuf);

    gemm_proj<<<dim3(M_ / 128, 1024 / 64), 256, 0, stream>>>(
        ybuf, wproj_t, bproj, out, M_, 1024, 1024);
}